// Round 8
// baseline (179.446 us; speedup 1.0000x reference)
//
#include <hip/hip_runtime.h>
#include <hip/hip_bf16.h>

#define N_NODES 50000
#define N_EDGES 800000
#define FEAT    128
#define N_TILES (N_NODES / 16)          // 3125
#define GEMM_BLOCKS 784                  // 782 needed (3125/4), padded to mult of 8
#define MAXD    32                       // slots per node; Poisson(16) P(deg>=32)~2.6e-4
#define OVF_CAP 16384
#define NODES_PER_GRP 6250               // 50000 / 8
#define CHUNK   2048
#define NCHUNK  ((N_EDGES + CHUNK - 1) / CHUNK)   // 391

using short8  = __attribute__((ext_vector_type(8))) short;
using float4v = __attribute__((ext_vector_type(4))) float;

// ---------------- workspace layout (ints) ----------------
// flag[16] | fill[50048] | ovf int2[16384] | slots uint[50000*32]
// | hidden ushort[50000*128] | Wbf ushort[16384]   total ~19.6 MB

__device__ __forceinline__ unsigned short f2b(float f) {
    __hip_bfloat16 h = __float2bfloat16(f);           // RNE
    return __builtin_bit_cast(unsigned short, h);
}

// zero fill + ovf cursor; detect int64-vs-int32 edge_index; convert W -> bf16 once
__global__ void k_init(const int* __restrict__ ei, const float* __restrict__ W,
                       int* __restrict__ flag, int* __restrict__ fill,
                       unsigned short* __restrict__ wbf) {
    int i = blockIdx.x * blockDim.x + threadIdx.x;
    if (i < N_NODES) fill[i] = 0;
    if (i < 4096) {                                   // 4096 float4 = 16384 elems
        float4v wv = *(const float4v*)(W + (size_t)i * 4);
        unsigned short* p = wbf + (size_t)i * 4;
        p[0] = f2b(wv[0]); p[1] = f2b(wv[1]); p[2] = f2b(wv[2]); p[3] = f2b(wv[3]);
    }
    if (blockIdx.x == 0 && threadIdx.x < 64) {
        unsigned long long m = __ballot(ei[2 * threadIdx.x + 1] != 0);
        if (threadIdx.x == 0) { flag[0] = (m == 0ULL) ? 1 : 0; flag[1] = 0; }
    }
}

// Fused, LDS-free: blocks [0,GEMM_BLOCKS) do GEMM (B-frags from global bf16 W,
// L1-resident 32KB); the rest do the XCD-grouped scatter at full occupancy.
__global__ __launch_bounds__(256) void k_fused(const float* __restrict__ x,
                                               const unsigned short* __restrict__ wbf,
                                               const float* __restrict__ bias,
                                               unsigned short* __restrict__ hidden,
                                               const int* __restrict__ ei,
                                               const float* __restrict__ wt,
                                               int* __restrict__ flag,
                                               int* __restrict__ fill,
                                               unsigned int* __restrict__ slots,
                                               int2* __restrict__ ovf) {
    const int t = threadIdx.x;

    if (blockIdx.x < GEMM_BLOCKS) {
        // ---------------- GEMM path ----------------
        const int wave = t >> 6;
        const int lane = t & 63;
        int tile = blockIdx.x * 4 + wave;
        if (tile >= N_TILES) tile = N_TILES - 1;    // clamp: redundant work, no divergence
        const int rowBase = tile * 16;
        const int m    = lane & 15;
        const int quad = lane >> 4;

        float4v acc[8];
        for (int i = 0; i < 8; ++i) acc[i] = (float4v){0.f, 0.f, 0.f, 0.f};

        for (int kk = 0; kk < 4; ++kk) {
            const int k0 = kk * 32 + quad * 8;
            const float* ap = x + (size_t)(rowBase + m) * FEAT + k0;
            float4v a0 = *(const float4v*)(ap);
            float4v a1 = *(const float4v*)(ap + 4);
            short8 af;
            for (int j = 0; j < 4; ++j) { af[j] = (short)f2b(a0[j]); af[4 + j] = (short)f2b(a1[j]); }
            for (int nt = 0; nt < 8; ++nt) {
                short8 bf = *(const short8*)(wbf + (size_t)(nt * 16 + m) * FEAT + k0);
                acc[nt] = __builtin_amdgcn_mfma_f32_16x16x32_bf16(af, bf, acc[nt], 0, 0, 0);
            }
        }

        const int r0 = rowBase + quad * 4;          // C/D: col=lane&15, row=quad*4+r
        for (int nt = 0; nt < 8; ++nt) {
            const int col = nt * 16 + m;
            const float bc = bias[col];
            for (int r = 0; r < 4; ++r) {
                hidden[(size_t)(r0 + r) * FEAT + col] = f2b(acc[nt][r] + bc);
            }
        }
    } else {
        // ---------------- scatter path (XCD-grouped) ----------------
        const int bid = blockIdx.x - GEMM_BLOCKS;
        const int grp = bid & 7;
        const int lo  = grp * NODES_PER_GRP;
        const int hi  = lo + NODES_PER_GRP;
        const int sh  = flag[0];
        const int e0  = (bid >> 3) * CHUNK + t;

        int dsts[8];
        #pragma unroll
        for (int i = 0; i < 8; ++i) {
            int e = e0 + i * 256;
            dsts[i] = (e < N_EDGES) ? ei[(size_t)e << sh] : -1;
        }
        #pragma unroll
        for (int i = 0; i < 8; ++i) {
            int e = e0 + i * 256;
            if (e >= N_EDGES) continue;
            int dst = dsts[i];
            if ((unsigned)dst >= N_NODES) dst = 0;
            if (dst < lo || dst >= hi) continue;
            int src = ei[(size_t)(N_EDGES + e) << sh];
            if ((unsigned)src >= N_NODES) src = 0;
            unsigned int rec = ((unsigned int)f2b(wt[e]) << 16) | (unsigned int)src;
            int pos = atomicAdd(&fill[dst], 1);
            if (pos < MAXD) {
                slots[(size_t)dst * MAXD + pos] = rec;
            } else {
                int op = atomicAdd(&flag[1], 1);
                if (op < OVF_CAP) { int2 r; r.x = dst; r.y = (int)rec; ovf[op] = r; }
            }
        }
    }
}

// out[node][:] = sum_slots w_e * hidden[src_e][:]
// wave per node; lane-group g (16 lanes) handles edge e+g; each lane loads 16B
// (8 bf16 feats) -> 1 gather instruction covers 4 edges. fp32 accumulate.
__global__ __launch_bounds__(256) void k_agg(const int* __restrict__ fill,
                                             const unsigned int* __restrict__ slots,
                                             const unsigned int* __restrict__ hid,
                                             const int* __restrict__ flag,
                                             const int2* __restrict__ ovf,
                                             float* __restrict__ out) {
    const int wave = threadIdx.x >> 6;
    const int lane = threadIdx.x & 63;
    const int node = blockIdx.x * 4 + wave;         // grid exact: 12500*4 = 50000
    const int grp  = lane >> 4;
    const int sub  = lane & 15;

    const int degf = fill[node];
    const int deg  = (degf > MAXD) ? MAXD : degf;
    const unsigned int* sl = slots + (size_t)node * MAXD;

    float acc[8];
    #pragma unroll
    for (int j = 0; j < 8; ++j) acc[j] = 0.f;

    for (int e = 0; e < deg; e += 4) {
        uint4 recs = *(const uint4*)(sl + e);                   // 16B broadcast
        unsigned rec = (grp < 2) ? (grp == 0 ? recs.x : recs.y)
                                 : (grp == 2 ? recs.z : recs.w);
        const bool v = (e + grp) < deg;
        const float w = v ? __uint_as_float(rec & 0xffff0000u) : 0.f;
        const unsigned src = v ? (rec & 0xffffu) : 0u;
        uint4 h = *((const uint4*)(hid + (size_t)src * 64) + sub);  // 16B/lane gather
        acc[0] = fmaf(w, __uint_as_float((h.x & 0xffffu) << 16), acc[0]);
        acc[1] = fmaf(w, __uint_as_float(h.x & 0xffff0000u),     acc[1]);
        acc[2] = fmaf(w, __uint_as_float((h.y & 0xffffu) << 16), acc[2]);
        acc[3] = fmaf(w, __uint_as_float(h.y & 0xffff0000u),     acc[3]);
        acc[4] = fmaf(w, __uint_as_float((h.z & 0xffffu) << 16), acc[4]);
        acc[5] = fmaf(w, __uint_as_float(h.z & 0xffff0000u),     acc[5]);
        acc[6] = fmaf(w, __uint_as_float((h.w & 0xffffu) << 16), acc[6]);
        acc[7] = fmaf(w, __uint_as_float(h.w & 0xffff0000u),     acc[7]);
    }

    // rare overflow edges folded in (entry i handled by lane-group i&3)
    if (degf > MAXD) {
        int n = flag[1]; if (n > OVF_CAP) n = OVF_CAP;
        for (int i = 0; i < n; ++i) {
            int2 r = ovf[i];
            if (r.x != node || (i & 3) != grp) continue;
            unsigned rec = (unsigned)r.y;
            float w = __uint_as_float(rec & 0xffff0000u);
            unsigned src = rec & 0xffffu;
            uint4 h = *((const uint4*)(hid + (size_t)src * 64) + sub);
            acc[0] = fmaf(w, __uint_as_float((h.x & 0xffffu) << 16), acc[0]);
            acc[1] = fmaf(w, __uint_as_float(h.x & 0xffff0000u),     acc[1]);
            acc[2] = fmaf(w, __uint_as_float((h.y & 0xffffu) << 16), acc[2]);
            acc[3] = fmaf(w, __uint_as_float(h.y & 0xffff0000u),     acc[3]);
            acc[4] = fmaf(w, __uint_as_float((h.z & 0xffffu) << 16), acc[4]);
            acc[5] = fmaf(w, __uint_as_float(h.z & 0xffff0000u),     acc[5]);
            acc[6] = fmaf(w, __uint_as_float((h.w & 0xffffu) << 16), acc[6]);
            acc[7] = fmaf(w, __uint_as_float(h.w & 0xffff0000u),     acc[7]);
        }
    }

    // combine the 4 lane-groups: butterfly over lane bits 4,5
    #pragma unroll
    for (int j = 0; j < 8; ++j) {
        float a = acc[j];
        a += __shfl_xor(a, 16, 64);
        a += __shfl_xor(a, 32, 64);
        acc[j] = a;
    }

    if (lane < 16) {
        float* o = out + (size_t)node * FEAT + sub * 8;
        *(float4*)(o)     = make_float4(acc[0], acc[1], acc[2], acc[3]);
        *(float4*)(o + 4) = make_float4(acc[4], acc[5], acc[6], acc[7]);
    }
}

extern "C" void kernel_launch(void* const* d_in, const int* in_sizes, int n_in,
                              void* d_out, int out_size, void* d_ws, size_t ws_size,
                              hipStream_t stream) {
    const float* x  = (const float*)d_in[0];
    const int*   ei = (const int*)d_in[1];
    const float* ew = (const float*)d_in[2];
    const float* W  = (const float*)d_in[3];
    const float* b  = (const float*)d_in[4];
    float* out = (float*)d_out;

    int*  flag = (int*)d_ws;
    int*  fill = flag + 16;
    int2* ovf  = (int2*)(fill + 50048);
    unsigned int* slots = (unsigned int*)(ovf + OVF_CAP);
    unsigned short* hidden = (unsigned short*)(slots + (size_t)N_NODES * MAXD);
    unsigned short* wbf = hidden + (size_t)N_NODES * FEAT;      // 16B-aligned

    k_init <<<(N_NODES + 255) / 256, 256, 0, stream>>>(ei, W, flag, fill, wbf);
    k_fused<<<GEMM_BLOCKS + NCHUNK * 8, 256, 0, stream>>>(x, wbf, b, hidden, ei, ew,
                                                          flag, fill, slots, ovf);
    k_agg  <<<N_NODES / 4, 256, 0, stream>>>(fill, slots, (const unsigned int*)hidden,
                                             flag, ovf, out);
}